// Round 9
// baseline (219.432 us; speedup 1.0000x reference)
//
#include <hip/hip_runtime.h>
#include <cstdint>
#include <cstddef>

typedef __bf16 bf16x8 __attribute__((ext_vector_type(8)));
typedef float f32x4 __attribute__((ext_vector_type(4)));
typedef float f32x16 __attribute__((ext_vector_type(16)));
typedef unsigned short ushort8 __attribute__((ext_vector_type(8)));
typedef unsigned u32x2 __attribute__((ext_vector_type(2)));
typedef float f4 __attribute__((ext_vector_type(4)));

__device__ __forceinline__ unsigned short f2bf(float f) {
    __bf16 b = (__bf16)f;
    return *(unsigned short*)&b;
}
__device__ __forceinline__ unsigned pk2bf(float a, float b) {
    __bf16 x = (__bf16)a, y = (__bf16)b;
    unsigned short ux = *(unsigned short*)&x, uy = *(unsigned short*)&y;
    return (unsigned)ux | ((unsigned)uy << 16);
}
__device__ __forceinline__ float bf2f(unsigned short u) {
    union { unsigned u; float f; } v; v.u = ((unsigned)u) << 16; return v.f;
}

#if __has_builtin(__builtin_amdgcn_exp2f)
#define EXP2(x) __builtin_amdgcn_exp2f(x)
#else
#define EXP2(x) exp2f(x)
#endif

// exchange high 32 lanes of x with low 32 lanes of y (v_permlane32_swap_b32)
__device__ __forceinline__ void pl32swap(unsigned& x, unsigned& y) {
#if __has_builtin(__builtin_amdgcn_permlane32_swap)
    auto r = __builtin_amdgcn_permlane32_swap(x, y, false, false);
    x = r[0]; y = r[1];
#else
    unsigned xs = (unsigned)__shfl_xor((int)x, 32, 64);
    unsigned ys = (unsigned)__shfl_xor((int)y, 32, 64);
    bool lo = ((threadIdx.x & 63) < 32);
    unsigned nx = lo ? x : ys;
    unsigned ny = lo ? xs : y;
    x = nx; y = ny;
#endif
}

// GLL: offset=0 form only (r4: nonzero imm NaN'd on the LDS-DMA path).
#define GLL(g, l) __builtin_amdgcn_global_load_lds( \
    (__attribute__((address_space(1))) void*)(g), \
    (__attribute__((address_space(3))) void*)(l), 16, 0, 0)

#define CS 0.18033688011112042f   /* 0.125 * log2(e) */
#define SPLITS 2                  /* key splits in attention */

// ---------------------------------------------------------------------------
// 1. prep: blocks <4096 convert the four 512x512 fp32 weights to bf16;
//    blocks >=4096 compute GroupNorm partial stats (merged: saves a launch).
// ---------------------------------------------------------------------------
__global__ __launch_bounds__(256) void prep(
    const float* __restrict__ wq, const float* __restrict__ wk,
    const float* __restrict__ wv, const float* __restrict__ wo,
    unsigned short* __restrict__ wb,
    const float* __restrict__ x, float* __restrict__ part)
{
    const int bid = blockIdx.x;
    if (bid < 4096) {
        int i = bid * 256 + threadIdx.x;
        const float* src = (i < 262144) ? wq : (i < 524288) ? wk : (i < 786432) ? wv : wo;
        wb[i] = f2bf(src[i & 262143]);
        return;
    }
    // GroupNorm stats: blk = (bg*4 + q)
    const int blk = bid - 4096;
    const int q = blk & 3, bg = blk >> 2;
    const f4* xv = (const f4*)(x + (size_t)bg * 65536 + q * 16384);
    float s = 0.f, sq = 0.f;
    for (int i = threadIdx.x; i < 4096; i += 256) {
        f4 v = xv[i];
        s  += v.x + v.y + v.z + v.w;
        sq += v.x * v.x + v.y * v.y + v.z * v.z + v.w * v.w;
    }
    #pragma unroll
    for (int off = 32; off > 0; off >>= 1) {
        s  += __shfl_xor(s, off, 64);
        sq += __shfl_xor(sq, off, 64);
    }
    __shared__ float red[8];
    const int w = threadIdx.x >> 6, lane = threadIdx.x & 63;
    if (lane == 0) { red[w] = s; red[4 + w] = sq; }
    __syncthreads();
    if (threadIdx.x == 0) {
        part[(bg * 4 + q) * 2]     = red[0] + red[1] + red[2] + red[3];
        part[(bg * 4 + q) * 2 + 1] = red[4] + red[5] + red[6] + red[7];
    }
}

// ---------------------------------------------------------------------------
// 2. GroupNorm apply -> h bf16 in [B*N, C] layout.
// ---------------------------------------------------------------------------
__global__ __launch_bounds__(256) void gn_apply(
    const float* __restrict__ x, const float* __restrict__ gamma,
    const float* __restrict__ beta, const float* __restrict__ part,
    unsigned short* __restrict__ h)
{
    const int q = blockIdx.x, bg = blockIdx.y;
    const int b = bg >> 5, g = bg & 31;
    float s = 0.f, sq = 0.f;
    #pragma unroll
    for (int j = 0; j < 4; ++j) {
        s  += part[(bg * 4 + j) * 2];
        sq += part[(bg * 4 + j) * 2 + 1];
    }
    const float mean = s * (1.f / 65536.f);
    const float rstd = rsqrtf(sq * (1.f / 65536.f) - mean * mean + 1e-5f);

    float gm[16], bt[16];
    #pragma unroll
    for (int c = 0; c < 16; ++c) {
        gm[c] = gamma[g * 16 + c] * rstd;
        bt[c] = beta[g * 16 + c];
    }
    const float* xg = x + (size_t)bg * 65536;
    const int n0 = q * 1024 + threadIdx.x * 4;
    float val[16][4];
    #pragma unroll
    for (int c = 0; c < 16; ++c) {
        f4 v = *(const f4*)&xg[(size_t)c * 4096 + n0];
        val[c][0] = (v.x - mean) * gm[c] + bt[c];
        val[c][1] = (v.y - mean) * gm[c] + bt[c];
        val[c][2] = (v.z - mean) * gm[c] + bt[c];
        val[c][3] = (v.w - mean) * gm[c] + bt[c];
    }
    #pragma unroll
    for (int nn = 0; nn < 4; ++nn) {
        ushort8 v0, v1;
        #pragma unroll
        for (int c = 0; c < 8; ++c)  v0[c]     = f2bf(val[c][nn]);
        #pragma unroll
        for (int c = 8; c < 16; ++c) v1[c - 8] = f2bf(val[c][nn]);
        unsigned short* dst = h + ((size_t)(b * 4096 + n0 + nn)) * 512 + g * 16;
        *(ushort8*)dst = v0;
        *(ushort8*)(dst + 8) = v1;
    }
}

// ---------------------------------------------------------------------------
// 3. QKV GEMM, 8-wave / 512-thread blocks (r8 gemm_out mechanism applied):
//    main batch 4 waves/SIMD, 256-block tail batch 2 waves/SIMD (was 1).
//    C[i,j] = sum_k A[i,k]*Bt[j,k] + bias; cols<1024 (Q,K) -> qkv bf16
//    (Q pre-scaled by CS); cols>=1024 (V) -> vt[bh][d][n] (fused transpose).
//    Wave grid 2x4: each wave 64x32 output, acc[4][2]=32 regs.
//    Staging: 1 GLL per thread per matrix (t*8 = srow*32+sc8, lane-linear).
// ---------------------------------------------------------------------------
__global__ __launch_bounds__(512, 2) void gemm_qkv(
    const unsigned short* __restrict__ A,   // [8192][512] bf16
    const unsigned short* __restrict__ Bt,  // [1536][512] bf16
    const float* __restrict__ bias0,
    const float* __restrict__ bias1,
    const float* __restrict__ bias2,
    unsigned short* __restrict__ outB,
    unsigned short* __restrict__ vtout)
{
    __shared__ __attribute__((aligned(16))) unsigned short As[128 * 32];
    __shared__ __attribute__((aligned(16))) unsigned short Bs[128 * 32];
    const int t = threadIdx.x;
    const int w = t >> 6, lane = t & 63;
    const int l15 = lane & 15, l4 = lane >> 4;
    const int bm = blockIdx.y, bn = blockIdx.x;
    const int wm = (w >> 2) * 64, wn = (w & 3) * 32;

    f32x4 acc[4][2] = {};

    const int srow = t >> 2, sc8 = (t & 3) * 8;
    const unsigned short* gA = A  + (size_t)(bm * 128 + srow) * 512 + sc8;
    const unsigned short* gB = Bt + (size_t)(bn * 128 + srow) * 512 + sc8;
    unsigned short* lA = &As[t * 8];
    unsigned short* lB = &Bs[t * 8];

    for (int k0 = 0; k0 < 512; k0 += 32) {
        __syncthreads();
        GLL(gA + k0, lA);
        GLL(gB + k0, lB);
        __syncthreads();

        bf16x8 af[4], bfr[2];
        #pragma unroll
        for (int mt = 0; mt < 4; ++mt)
            af[mt] = *(const bf16x8*)&As[(wm + mt * 16 + l15) * 32 + l4 * 8];
        #pragma unroll
        for (int nt = 0; nt < 2; ++nt)
            bfr[nt] = *(const bf16x8*)&Bs[(wn + nt * 16 + l15) * 32 + l4 * 8];
        #pragma unroll
        for (int mt = 0; mt < 4; ++mt)
            #pragma unroll
            for (int nt = 0; nt < 2; ++nt)
                acc[mt][nt] = __builtin_amdgcn_mfma_f32_16x16x32_bf16(
                    af[mt], bfr[nt], acc[mt][nt], 0, 0, 0);
    }

    #pragma unroll
    for (int nt = 0; nt < 2; ++nt) {
        int col = bn * 128 + wn + nt * 16 + l15;
        const float* bp = (col < 512) ? bias0 : (col < 1024) ? bias1 : bias2;
        float bv = bp[col & 511];
        if (col < 1024) {                    // Q (pre-scaled) / K -> qkv [8192][1024]
            float sc = (col < 512) ? CS : 1.0f;
            #pragma unroll
            for (int mt = 0; mt < 4; ++mt)
                #pragma unroll
                for (int r = 0; r < 4; ++r) {
                    int row = bm * 128 + wm + mt * 16 + l4 * 4 + r;
                    outB[(size_t)row * 1024 + col] = f2bf((acc[mt][nt][r] + bv) * sc);
                }
        } else {                             // V -> vt[bh][d][n] directly
            int hd = col - 1024;             // h*64 + d
            #pragma unroll
            for (int mt = 0; mt < 4; ++mt) {
                int m = bm * 128 + wm + mt * 16 + l4 * 4;   // n base (r=0)
                int bb = m >> 12, n = m & 4095;
                unsigned u0 = pk2bf(acc[mt][nt][0] + bv, acc[mt][nt][1] + bv);
                unsigned u1 = pk2bf(acc[mt][nt][2] + bv, acc[mt][nt][3] + bv);
                unsigned short* dst = vtout +
                    ((size_t)(bb * 8 + (hd >> 6)) * 64 + (hd & 63)) * 4096 + n;
                *(u32x2*)dst = (u32x2){u0, u1};
            }
        }
    }
}

// ---------------------------------------------------------------------------
// 3b. Out-projection GEMM with FUSED split-combine (replaces combine_o):
//     B[m][k] = (opart0[m][k] + opart1[m][k]) / (l0[m] + l1[m]) built in
//     registers during staging (A stays GLL; B becomes reg-stage+ds_write).
//     h = k0>>6 exactly (since (k0&63)+sc8 < 64), so the 8 per-head inverse
//     denominators are precomputed once. O-chunk loads prefetched 1 k-step
//     ahead. 8 waves -> 2 waves/SIMD at the 1-block/CU grid (r8 win kept).
//     C[c,m] = sum_k Wo[c,k]*O[m,k]; out fp32 [B,C,H,W] + bias + residual.
// ---------------------------------------------------------------------------
__global__ __launch_bounds__(512, 2) void gemm_out(
    const unsigned short* __restrict__ A,      // Wo bf16 [512][512]
    const unsigned short* __restrict__ opart,  // [SPLITS][65536][64] bf16
    const float* __restrict__ lbuf,            // [SPLITS][65536]
    const float* __restrict__ bias,
    const float* __restrict__ resid,
    float* __restrict__ outF)
{
    __shared__ __attribute__((aligned(16))) unsigned short As[128 * 32];
    __shared__ __attribute__((aligned(16))) unsigned short Bs[128 * 32];
    const int t = threadIdx.x;
    const int w = t >> 6, lane = t & 63;
    const int l15 = lane & 15, l4 = lane >> 4;
    const int bm = blockIdx.y, bn = blockIdx.x;
    const int wm = (w >> 2) * 64, wn = (w & 3) * 32;

    f32x4 acc[4][2] = {};

    const int srow = t >> 2, sc8 = (t & 3) * 8;
    const unsigned short* gA = A + (size_t)(bm * 128 + srow) * 512 + sc8;
    unsigned short* lA = &As[t * 8];
    unsigned short* lB = &Bs[t * 8];

    // O-row bookkeeping for the staged B row m = bn*128 + srow
    const int m = bn * 128 + srow;
    const int bb = m >> 12, q = m & 4095;
    const size_t prow0 = (size_t)(bb * 8) * 4096 + q;       // head-0 row
    float inv[8];
    #pragma unroll
    for (int hh = 0; hh < 8; ++hh) {
        size_t pr = prow0 + (size_t)hh * 4096;
        inv[hh] = 1.f / (lbuf[pr] + lbuf[65536 + pr]);
    }
    const unsigned short* gO0 = opart + prow0 * 64;
    const unsigned short* gO1 = gO0 + (size_t)65536 * 64;
    // chunk offset for k-step k0: head stride 4096 rows x 64 = 262144 elems
    //   off(k0) = (k0>>6)*262144 + (k0&32) + sc8   (d = (k0&63)+sc8 < 64)

    ushort8 o0 = *(const ushort8*)(gO0 + sc8);
    ushort8 o1 = *(const ushort8*)(gO1 + sc8);

    for (int k0 = 0; k0 < 512; k0 += 32) {
        // combine current chunk in registers
        float iv = inv[k0 >> 6];
        ushort8 bv8;
        #pragma unroll
        for (int i = 0; i < 8; ++i)
            bv8[i] = f2bf((bf2f(o0[i]) + bf2f(o1[i])) * iv);
        // prefetch next chunk (hides under barrier + MFMA)
        if (k0 < 480) {
            size_t noff = (size_t)((k0 + 32) >> 6) * 262144 + ((k0 + 32) & 32) + sc8;
            o0 = *(const ushort8*)(gO0 + noff);
            o1 = *(const ushort8*)(gO1 + noff);
        }
        __syncthreads();
        GLL(gA + k0, lA);
        *(ushort8*)lB = bv8;
        __syncthreads();

        bf16x8 af[4], bfr[2];
        #pragma unroll
        for (int mt = 0; mt < 4; ++mt)
            af[mt] = *(const bf16x8*)&As[(wm + mt * 16 + l15) * 32 + l4 * 8];
        #pragma unroll
        for (int nt = 0; nt < 2; ++nt)
            bfr[nt] = *(const bf16x8*)&Bs[(wn + nt * 16 + l15) * 32 + l4 * 8];
        #pragma unroll
        for (int mt = 0; mt < 4; ++mt)
            #pragma unroll
            for (int nt = 0; nt < 2; ++nt)
                acc[mt][nt] = __builtin_amdgcn_mfma_f32_16x16x32_bf16(
                    af[mt], bfr[nt], acc[mt][nt], 0, 0, 0);
    }

    #pragma unroll
    for (int mt = 0; mt < 4; ++mt)
        #pragma unroll
        for (int nt = 0; nt < 2; ++nt)
            #pragma unroll
            for (int r = 0; r < 4; ++r) {
                int c = bm * 128 + wm + mt * 16 + l4 * 4 + r;
                int mm = bn * 128 + wn + nt * 16 + l15;
                int b = mm >> 12, n = mm & 4095;
                size_t idx = ((size_t)(b * 512 + c)) * 4096 + n;
                outF[idx] = acc[mt][nt][r] + bias[c] + resid[idx];
            }
}

// ---------------------------------------------------------------------------
// 4. Flash attention — the r0/r7 structure, UNCHANGED (best measured:
//    84.7-88.5 us, noise band). 32x32x16 MFMA, 64 q/wave, 2-way key split,
//    reg-staged [64][72] padded tiles, two barriers/tile, no setprio
//    (r6: −10%), scalar row sums, epilogue overlays dead K/V (18.4 KB LDS).
//    Plateau: MfmaUtil+VALUBusy ~86% = SIMD issue-port saturation at the
//    algorithm's VALU:MFMA mix, invariant across 2-3 blocks/CU (r0/r2/r3).
// ---------------------------------------------------------------------------
__global__ __launch_bounds__(256, 2) void attn_kernel(
    const unsigned short* __restrict__ qkv, const unsigned short* __restrict__ vt,
    unsigned short* __restrict__ opart, float* __restrict__ lbuf)
{
    __shared__ __attribute__((aligned(16))) unsigned short Sh[2 * 64 * 72];
    unsigned short* KsB  = Sh;
    unsigned short* VtsB = Sh + 64 * 72;

    const int bh = blockIdx.y, b = bh >> 3, h = bh & 7;
    const int qbase = blockIdx.x * 256;
    const int s = blockIdx.z, ks0 = s * 2048;
    const int t = threadIdx.x, w = t >> 6, lane = t & 63;
    const int l31 = lane & 31, h5 = lane >> 5;

    const unsigned short* Qg = qkv + ((size_t)(b * 4096 + qbase + w * 64)) * 1024 + h * 64;
    const unsigned short* Kg = qkv + ((size_t)(b * 4096 + ks0)) * 1024 + 512 + h * 64;
    const unsigned short* Vg = vt + ((size_t)bh) * 64 * 4096 + ks0;

    // Q fragments (B-operand, persistent): q=qt*32+l31, d=kc*16+h5*8+j
    bf16x8 qf[2][4];
    #pragma unroll
    for (int qt = 0; qt < 2; ++qt)
        #pragma unroll
        for (int kc = 0; kc < 4; ++kc)
            qf[qt][kc] = *(const bf16x8*)(Qg + (size_t)(qt * 32 + l31) * 1024 + kc * 16 + h5 * 8);

    f32x16 Oacc[2][2] = {};      // [dt][qt], C-layout: col=q, row=d
    float li[2] = {0.f, 0.f};

    // staging: 256 threads x 32 B for each of K (8 KB) and V^T (8 KB)
    const int sr = t >> 2, sc = (t & 3) * 16;
    const unsigned short* gK = Kg + (size_t)sr * 1024 + sc;
    const unsigned short* gV = Vg + (size_t)sr * 4096 + sc;
    unsigned short* lK = KsB + sr * 72 + sc;
    unsigned short* lV = VtsB + sr * 72 + sc;

    ushort8 kr[2], vr[2];
    kr[0] = *(const ushort8*)(gK);
    kr[1] = *(const ushort8*)(gK + 8);
    vr[0] = *(const ushort8*)(gV);
    vr[1] = *(const ushort8*)(gV + 8);

    for (int kt = 0; kt < 32; ++kt) {
        __syncthreads();
        *(ushort8*)(lK)     = kr[0];
        *(ushort8*)(lK + 8) = kr[1];
        *(ushort8*)(lV)     = vr[0];
        *(ushort8*)(lV + 8) = vr[1];
        __syncthreads();
        if (kt < 31) {   // prefetch next tile into registers
            const unsigned short* nk = gK + (size_t)(kt + 1) * 65536;
            const unsigned short* nv = gV + (kt + 1) * 64;
            kr[0] = *(const ushort8*)(nk);
            kr[1] = *(const ushort8*)(nk + 8);
            vr[0] = *(const ushort8*)(nv);
            vr[1] = *(const ushort8*)(nv + 8);
        }

        // ---- S^T tiles: St[qt][ct] = K(ct) @ Q(qt)^T (scale pre-folded) ----
        f32x16 St[2][2] = {};
        #pragma unroll
        for (int ct = 0; ct < 2; ++ct)
            #pragma unroll
            for (int kc = 0; kc < 4; ++kc) {
                bf16x8 kf = *(const bf16x8*)(KsB + (ct * 32 + l31) * 72 + kc * 16 + h5 * 8);
                St[0][ct] = __builtin_amdgcn_mfma_f32_32x32x16_bf16(kf, qf[0][kc], St[0][ct], 0, 0, 0);
                St[1][ct] = __builtin_amdgcn_mfma_f32_32x32x16_bf16(kf, qf[1][kc], St[1][ct], 0, 0, 0);
            }

        // ---- p = exp2(S'); per-lane row sums; pack to PV B-operand ----
        union PU { unsigned u[4]; bf16x8 v; };
        PU pf[2][4];
        #pragma unroll
        for (int qt = 0; qt < 2; ++qt) {
            #pragma unroll
            for (int ct = 0; ct < 2; ++ct)
                #pragma unroll
                for (int r = 0; r < 16; ++r)
                    St[qt][ct][r] = EXP2(St[qt][ct][r]);
            float s0 = 0.f, s1 = 0.f;
            #pragma unroll
            for (int ct = 0; ct < 2; ++ct) {
                s0 += ((St[qt][ct][0] + St[qt][ct][1]) + (St[qt][ct][2] + St[qt][ct][3]))
                    + ((St[qt][ct][4] + St[qt][ct][5]) + (St[qt][ct][6] + St[qt][ct][7]));
                s1 += ((St[qt][ct][8] + St[qt][ct][9]) + (St[qt][ct][10] + St[qt][ct][11]))
                    + ((St[qt][ct][12] + St[qt][ct][13]) + (St[qt][ct][14] + St[qt][ct][15]));
            }
            li[qt] += s0 + s1;

            #pragma unroll
            for (int ct = 0; ct < 2; ++ct) {
                unsigned pk0 = pk2bf(St[qt][ct][0],  St[qt][ct][1]);
                unsigned pk1 = pk2bf(St[qt][ct][2],  St[qt][ct][3]);
                unsigned pk2 = pk2bf(St[qt][ct][4],  St[qt][ct][5]);
                unsigned pk3 = pk2bf(St[qt][ct][6],  St[qt][ct][7]);
                unsigned pk4 = pk2bf(St[qt][ct][8],  St[qt][ct][9]);
                unsigned pk5 = pk2bf(St[qt][ct][10], St[qt][ct][11]);
                unsigned pk6 = pk2bf(St[qt][ct][12], St[qt][ct][13]);
                unsigned pk7 = pk2bf(St[qt][ct][14], St[qt][ct][15]);
                pl32swap(pk0, pk2); pl32swap(pk1, pk3);
                pl32swap(pk4, pk6); pl32swap(pk5, pk7);
                pf[qt][ct * 2].u[0] = pk0; pf[qt][ct * 2].u[1] = pk1;
                pf[qt][ct * 2].u[2] = pk2; pf[qt][ct * 2].u[3] = pk3;
                pf[qt][ct * 2 + 1].u[0] = pk4; pf[qt][ct * 2 + 1].u[1] = pk5;
                pf[qt][ct * 2 + 1].u[2] = pk6; pf[qt][ct * 2 + 1].u[3] = pk7;
            }
        }

        // ---- O^T += V^T(dt) @ P^T(kk) ----
        #pragma unroll
        for (int kk = 0; kk < 4; ++kk)
            #pragma unroll
            for (int dt = 0; dt < 2; ++dt) {
                bf16x8 vf = *(const bf16x8*)(VtsB + (dt * 32 + l31) * 72 + kk * 16 + h5 * 8);
                Oacc[dt][0] = __builtin_amdgcn_mfma_f32_32x32x16_bf16(vf, pf[0][kk].v, Oacc[dt][0], 0, 0, 0);
                Oacc[dt][1] = __builtin_amdgcn_mfma_f32_32x32x16_bf16(vf, pf[1][kk].v, Oacc[dt][1], 0, 0, 0);
            }
    }

    // ---- epilogue: UNNORMALIZED partials. l -> lbuf, O -> opart (bf16) ----
    #pragma unroll
    for (int qt = 0; qt < 2; ++qt) {
        float lf = li[qt] + __shfl_xor(li[qt], 32, 64);
        if (h5 == 0)
            lbuf[((size_t)s * 16 + bh) * 4096 + qbase + w * 64 + qt * 32 + l31] = lf;
    }

    // all waves done reading K/V tiles -> overlay per-wave 32x72 scratch
    __syncthreads();
    unsigned short* Eb = Sh + w * (32 * 72);
    #pragma unroll
    for (int qt = 0; qt < 2; ++qt) {
        #pragma unroll
        for (int dt = 0; dt < 2; ++dt)
            #pragma unroll
            for (int p = 0; p < 8; ++p) {
                int d = dt * 32 + 2 * (p & 1) + 8 * (p >> 1) + 4 * h5;
                unsigned u = pk2bf(Oacc[dt][qt][2 * p], Oacc[dt][qt][2 * p + 1]);
                *(unsigned*)&Eb[l31 * 72 + d] = u;
            }
        // same-wave read-back, 16B stores of [q][64] rows (2 lanes per row)
        unsigned short* Og = opart +
            (((size_t)s * 16 + bh) * 4096 + qbase + w * 64 + qt * 32) * 64;
        #pragma unroll
        for (int i = 0; i < 4; ++i) {
            int c8 = h5 * 4 + i;
            ushort8 val = *(const ushort8*)&Eb[l31 * 72 + c8 * 8];
            *(ushort8*)(Og + (size_t)l31 * 64 + c8 * 8) = val;
        }
    }
}

// ---------------------------------------------------------------------------
// launch
// ---------------------------------------------------------------------------
extern "C" void kernel_launch(void* const* d_in, const int* in_sizes, int n_in,
                              void* d_out, int out_size, void* d_ws, size_t ws_size,
                              hipStream_t stream) {
    const float* x     = (const float*)d_in[0];
    const float* gamma = (const float*)d_in[1];
    const float* beta  = (const float*)d_in[2];
    const float* Wq    = (const float*)d_in[3];
    const float* bq    = (const float*)d_in[4];
    const float* Wk    = (const float*)d_in[5];
    const float* bk    = (const float*)d_in[6];
    const float* Wv    = (const float*)d_in[7];
    const float* bv    = (const float*)d_in[8];
    const float* Wo    = (const float*)d_in[9];
    const float* bo    = (const float*)d_in[10];
    float* out = (float*)d_out;

    char* ws = (char*)d_ws;
    const size_t MB = 1024 * 1024;
    // Lifetime-overlapped layout (peak 60 MiB):
    //   wb     @  0  (2 MiB)   prep .. gemm_out
    //   gnpart @  2  (4 KiB)
    //   qkv    @  3  (16 MiB)  [8192][1024] Q|K   (gemm_qkv .. attn)
    //   vtb    @ 19  (8 MiB)   [bh][64][4096]     (gemm_qkv .. attn)
    //   h      @ 27  (8 MiB)   gn_apply .. gemm_qkv  (dead before attn)
    //   opart  @ 27  (16 MiB)  attn .. gemm_out      (overlays h)
    //   lbuf   @ 59  (512 KiB) attn .. gemm_out
    unsigned short* wb     = (unsigned short*)(ws);
    float*          gnpart = (float*)(ws + 2 * MB);
    unsigned short* qkv    = (unsigned short*)(ws + 3 * MB);
    unsigned short* vtb    = (unsigned short*)(ws + 19 * MB);
    unsigned short* h      = (unsigned short*)(ws + 27 * MB);
    unsigned short* opart  = (unsigned short*)(ws + 27 * MB);
    float*          lbuf   = (float*)(ws + 59 * MB);

    // weights->bf16 (4096 blocks) + GN stats (256 blocks) in one launch
    prep<<<dim3(4352), dim3(256), 0, stream>>>(Wq, Wk, Wv, Wo, wb, x, gnpart);
    gn_apply<<<dim3(4, 64), dim3(256), 0, stream>>>(x, gamma, beta, gnpart, h);

    // fused qkv = h @ [Wq;Wk;Wv]^T + b; Q/K -> qkv (stride 1024), V -> vtb
    gemm_qkv<<<dim3(12, 64), dim3(512), 0, stream>>>(
        h, wb, bq, bk, bv, qkv, vtb);

    attn_kernel<<<dim3(16, 16, SPLITS), dim3(256), 0, stream>>>(qkv, vtb, opart, lbuf);

    // out = x + (combine(opart)/l @ Wo^T + bo)^T, combine fused into staging
    gemm_out<<<dim3(64, 4), dim3(512), 0, stream>>>(
        wb + 786432, opart, lbuf, bo, x, out);
}